// Round 10
// baseline (374.156 us; speedup 1.0000x reference)
//
#include <hip/hip_runtime.h>
#include <math.h>

#define DIM 128
#define DEMB 64
#define CHUNK 4096  // edges per block in bucket_scatter

typedef __attribute__((ext_vector_type(8))) short bf16x8;
typedef __attribute__((ext_vector_type(4))) float f32x4;

// ---------------- bf16 pack/unpack helpers ----------------

__device__ __forceinline__ unsigned pack_bf16x2(float a, float b) {
    unsigned ua = __float_as_uint(a);
    unsigned ub = __float_as_uint(b);
    ua = (ua + 0x7fffu + ((ua >> 16) & 1u)) >> 16;          // low half  = bf16(a)
    ub = (ub + 0x7fffu + ((ub >> 16) & 1u)) & 0xffff0000u;  // high half = bf16(b)
    return ua | ub;
}
__device__ __forceinline__ float lo_bf16(unsigned v) { return __uint_as_float(v << 16); }
__device__ __forceinline__ float hi_bf16(unsigned v) { return __uint_as_float(v & 0xffff0000u); }

// ---------------- convert x (f32) -> packed bf16 ----------------

__global__ __launch_bounds__(256) void convert_kernel(const float* __restrict__ in,
                                                      unsigned* __restrict__ out, int n4) {
    int i = blockIdx.x * 256 + threadIdx.x;
    int stride = gridDim.x * 256;
    for (; i < n4; i += stride) {
        float4 v = reinterpret_cast<const float4*>(in)[i];
        uint2 pk = {pack_bf16x2(v.x, v.y), pack_bf16x2(v.z, v.w)};
        reinterpret_cast<uint2*>(out)[i] = pk;
    }
}

// ------- prep: W1 (f32 [k][n]) -> W1t packed bf16, n-major [n][k] (128x64 uints) -------

__global__ __launch_bounds__(256) void prep_w1t(const float* __restrict__ W1,
                                                unsigned* __restrict__ W1t) {
    int i = blockIdx.x * 256 + threadIdx.x;  // [0, 128*64)
    if (i >= 128 * 64) return;
    int n = i >> 6, k2 = i & 63;
    float a = W1[(size_t)(2 * k2) * DIM + n];
    float b = W1[(size_t)(2 * k2 + 1) * DIM + n];
    W1t[i] = pack_bf16x2(a, b);
}

// ---------------- bucketed CSR build ----------------
// bucket b = dst >> 8 (256 nodes/bucket); nbuck = ceil(n_nodes/256) <= 384

__global__ __launch_bounds__(256) void bucket_count(const int* __restrict__ dst,
                                                    int* __restrict__ bcnt,
                                                    int n_edges, int nbuck) {
    __shared__ int h[384];
    for (int i = threadIdx.x; i < nbuck; i += 256) h[i] = 0;
    __syncthreads();
    int i = blockIdx.x * 256 + threadIdx.x;
    int stride = gridDim.x * 256;
    for (; i < n_edges; i += stride) atomicAdd(&h[__builtin_nontemporal_load(&dst[i]) >> 8], 1);
    __syncthreads();
    for (int i2 = threadIdx.x; i2 < nbuck; i2 += 256)
        if (h[i2]) atomicAdd(&bcnt[i2], h[i2]);
}

__global__ __launch_bounds__(512) void bucket_scan(const int* __restrict__ bcnt,
                                                   int* __restrict__ bstart,
                                                   int* __restrict__ bcursor,
                                                   int nbuck, int n_edges) {
    __shared__ int sm[512];
    int tid = threadIdx.x;
    int v = (tid < nbuck) ? bcnt[tid] : 0;
    sm[tid] = v;
    __syncthreads();
    for (int off = 1; off < 512; off <<= 1) {
        int t = (tid >= off) ? sm[tid - off] : 0;
        __syncthreads();
        if (tid >= off) sm[tid] += t;
        __syncthreads();
    }
    if (tid < nbuck) {
        int e = sm[tid] - v;
        bstart[tid] = e;
        bcursor[tid] = e;
    }
    if (tid == 0) bstart[nbuck] = n_edges;
}

// direct ranked scatter: count -> reserve -> rank+write.
__global__ __launch_bounds__(256) void bucket_scatter(const int* __restrict__ src,
                                                      const int* __restrict__ dst,
                                                      int* __restrict__ bcursor,
                                                      unsigned* __restrict__ binned,
                                                      int n_edges, int nbuck) {
    __shared__ int cnt[384], base[384];
    int tid = threadIdx.x;
    int e0 = blockIdx.x * CHUNK;
    int ne = min(CHUNK, n_edges - e0);
    for (int i = tid; i < nbuck; i += 256) cnt[i] = 0;
    __syncthreads();
    for (int j = tid; j < ne; j += 256)
        atomicAdd(&cnt[__builtin_nontemporal_load(&dst[e0 + j]) >> 8], 1);
    __syncthreads();
    for (int b = tid; b < nbuck; b += 256) {
        int c = cnt[b];
        base[b] = c ? atomicAdd(&bcursor[b], c) : 0;
        cnt[b] = 0;
    }
    __syncthreads();
    for (int j = tid; j < ne; j += 256) {
        int d = dst[e0 + j];
        int s = __builtin_nontemporal_load(&src[e0 + j]);
        int b = d >> 8;
        int r = atomicAdd(&cnt[b], 1);
        binned[base[b] + r] = ((unsigned)s << 8) | (unsigned)(d & 255);
    }
}

// one block per bucket: per-node counts, scan, CSR scatter (all writes L2-local)
__global__ __launch_bounds__(256) void bucket_csr(const unsigned* __restrict__ binned,
                                                  const int* __restrict__ bstart,
                                                  int* __restrict__ counts,
                                                  int* __restrict__ rowstart,
                                                  int* __restrict__ ssorted,
                                                  int n_nodes) {
    __shared__ int sm[256], cur[256];
    __shared__ int cntv[256];
    int b = blockIdx.x;
    int bs = bstart[b], be = bstart[b + 1];
    int node0 = b << 8;
    int tid = threadIdx.x;
    cntv[tid] = 0;
    __syncthreads();
    for (int j = bs + tid; j < be; j += 256) atomicAdd(&cntv[binned[j] & 255u], 1);
    __syncthreads();
    int v = cntv[tid];
    sm[tid] = v;
    __syncthreads();
    for (int off = 1; off < 256; off <<= 1) {
        int t = (tid >= off) ? sm[tid - off] : 0;
        __syncthreads();
        if (tid >= off) sm[tid] += t;
        __syncthreads();
    }
    int excl = sm[tid] - v;
    int node = node0 + tid;
    if (node < n_nodes) {
        counts[node] = v;
        rowstart[node] = bs + excl;
    }
    cur[tid] = excl;
    __syncthreads();
    for (int j = bs + tid; j < be; j += 256) {
        unsigned e = binned[j];
        int p = atomicAdd(&cur[(int)(e & 255u)], 1);
        ssorted[bs + p] = (int)(e >> 8);
    }
}

// ------- GCN layer 1 aggregate: 2 edges per VMEM instr (half-wave per row) -------
// lanes 0-31 load neighbor j's row (uint2/lane = 256B), lanes 32-63 neighbor j+1's.
// Each lane owns channels 4c..4c+3; cross-half shfl_xor(32) reduce at the end.

__global__ __launch_bounds__(256) void agg_kernel(const unsigned* __restrict__ xh,
                                                  const int* __restrict__ rowstart,
                                                  const int* __restrict__ counts,
                                                  const int* __restrict__ ssorted,
                                                  unsigned* __restrict__ Ah, int n_nodes) {
    int wave = (blockIdx.x * 256 + threadIdx.x) >> 6;
    int lane = threadIdx.x & 63;
    if (wave >= n_nodes) return;
    int base = rowstart[wave];
    int deg = counts[wave];
    int h = lane >> 5, c = lane & 31;
    const uint2* xp = reinterpret_cast<const uint2*>(xh) + c;  // + s*32
    float a0 = 0.f, a1 = 0.f, a2 = 0.f, a3 = 0.f;
    int bulk = deg & ~7;
    int j0 = 0;
    for (; j0 < bulk; j0 += 8) {
        int s0 = __builtin_nontemporal_load(&ssorted[base + j0 + 0 + h]);
        int s1 = __builtin_nontemporal_load(&ssorted[base + j0 + 2 + h]);
        int s2 = __builtin_nontemporal_load(&ssorted[base + j0 + 4 + h]);
        int s3 = __builtin_nontemporal_load(&ssorted[base + j0 + 6 + h]);
        uint2 v0 = xp[(size_t)s0 * 32];
        uint2 v1 = xp[(size_t)s1 * 32];
        uint2 v2 = xp[(size_t)s2 * 32];
        uint2 v3 = xp[(size_t)s3 * 32];
        a0 += (lo_bf16(v0.x) + lo_bf16(v1.x)) + (lo_bf16(v2.x) + lo_bf16(v3.x));
        a1 += (hi_bf16(v0.x) + hi_bf16(v1.x)) + (hi_bf16(v2.x) + hi_bf16(v3.x));
        a2 += (lo_bf16(v0.y) + lo_bf16(v1.y)) + (lo_bf16(v2.y) + lo_bf16(v3.y));
        a3 += (hi_bf16(v0.y) + hi_bf16(v1.y)) + (hi_bf16(v2.y) + hi_bf16(v3.y));
    }
    int rem = deg - bulk;
    if (rem > 0) {
        int dm1 = deg - 1;
#pragma unroll
        for (int i = 0; i < 4; i++) {
            int e = j0 + 2 * i + h;
            int s = __builtin_nontemporal_load(&ssorted[base + min(e, dm1)]);
            uint2 v = xp[(size_t)s * 32];
            unsigned mx = (e < deg) ? v.x : 0u;
            unsigned my = (e < deg) ? v.y : 0u;
            a0 += lo_bf16(mx);
            a1 += hi_bf16(mx);
            a2 += lo_bf16(my);
            a3 += hi_bf16(my);
        }
    }
    a0 += __shfl_xor(a0, 32);
    a1 += __shfl_xor(a1, 32);
    a2 += __shfl_xor(a2, 32);
    a3 += __shfl_xor(a3, 32);
    if (h == 0) {
        float inv = 1.f / fmaxf((float)deg, 1.f);
        unsigned lo = pack_bf16x2(a0 * inv, a1 * inv);
        unsigned hi = pack_bf16x2(a2 * inv, a3 * inv);
        unsigned long long pk = (unsigned long long)lo | ((unsigned long long)hi << 32);
        __builtin_nontemporal_store(
            pk, reinterpret_cast<unsigned long long*>(Ah + (size_t)wave * 64 + 2 * c));
    }
}

// ------- H = relu(A @ W1 + b1) via MFMA (bf16 in, f32 acc, bf16 out) -------

__global__ __launch_bounds__(256) void gemm1_mfma(const unsigned* __restrict__ Ah,
                                                  const unsigned* __restrict__ W1t,
                                                  const float* __restrict__ b1,
                                                  unsigned* __restrict__ Hh, int n_rows) {
    __shared__ unsigned Wt[128 * 68];  // [n][k2] padded (34 KB)
    int tid = threadIdx.x;
#pragma unroll
    for (int i = 0; i < 32; i++) {
        int idx = i * 256 + tid;  // 0..8191
        Wt[(idx >> 6) * 68 + (idx & 63)] = W1t[idx];
    }
    __syncthreads();
    int wv = tid >> 6, l = tid & 63;
    int r0w = blockIdx.x * 64 + wv * 16;
    int arow = r0w + (l & 15);
    int arowc = min(arow, n_rows - 1);
    int kgrp = l >> 4;
    const bf16x8* ap = reinterpret_cast<const bf16x8*>(Ah + (size_t)arowc * 64);
    bf16x8 afrag[4];
#pragma unroll
    for (int s = 0; s < 4; s++) afrag[s] = ap[s * 4 + kgrp];

    f32x4 acc[8];
#pragma unroll
    for (int nt = 0; nt < 8; nt++) {
        float bias = b1[nt * 16 + (l & 15)];
        acc[nt] = {bias, bias, bias, bias};
    }
#pragma unroll
    for (int s = 0; s < 4; s++) {
#pragma unroll
        for (int nt = 0; nt < 8; nt++) {
            bf16x8 bfrag = *reinterpret_cast<const bf16x8*>(
                &Wt[(nt * 16 + (l & 15)) * 68 + s * 16 + kgrp * 4]);
            acc[nt] = __builtin_amdgcn_mfma_f32_16x16x32_bf16(afrag[s], bfrag, acc[nt], 0, 0, 0);
        }
    }
    bool even = (l & 1) == 0;
#pragma unroll
    for (int nt = 0; nt < 8; nt++) {
#pragma unroll
        for (int j = 0; j < 4; j++) {
            float v = fmaxf(acc[nt][j], 0.f);
            float vp = __shfl_xor(v, 1);
            int r = r0w + ((l >> 4) << 2) + j;
            if (even && r < n_rows) {
                Hh[(size_t)r * 64 + nt * 8 + ((l & 15) >> 1)] = pack_bf16x2(v, vp);
            }
        }
    }
}

// ------- GCN layer 2 at target nodes only: mean-agg of Hh then @W2 + b2 -------

__global__ __launch_bounds__(256) void target_kernel(const unsigned* __restrict__ Hh,
                                                     const float* __restrict__ W2,
                                                     const float* __restrict__ b2,
                                                     const int* __restrict__ rowstart,
                                                     const int* __restrict__ counts,
                                                     const int* __restrict__ ssorted,
                                                     const int* __restrict__ dnum,
                                                     const int* __restrict__ tf_idx,
                                                     const int* __restrict__ gene_idx,
                                                     float* __restrict__ emb, int T, int ntar) {
    __shared__ float W2s[DIM * DEMB];  // 32 KB
    __shared__ float aggS[4][DIM];
    int tid = threadIdx.x;
    for (int i = 0; i < 8; i++) {
        int idx = (i * 256 + tid) * 4;
        *reinterpret_cast<float4*>(&W2s[idx]) = *reinterpret_cast<const float4*>(&W2[idx]);
    }
    int wv = tid >> 6, lane = tid & 63;
    int i = blockIdx.x * 4 + wv;
    int num = dnum[0];
    if (i < ntar) {
        int idx = (i < T) ? tf_idx[i] : gene_idx[i - T];
        int node = num + idx;
        int base = rowstart[node];
        int deg = counts[node];
        int h = lane >> 5, c = lane & 31;
        const uint2* hp = reinterpret_cast<const uint2*>(Hh) + c;
        float a0 = 0.f, a1 = 0.f, a2 = 0.f, a3 = 0.f;
        int bulk = deg & ~7;
        int j0 = 0;
        for (; j0 < bulk; j0 += 8) {
            int s0 = ssorted[base + j0 + 0 + h];
            int s1 = ssorted[base + j0 + 2 + h];
            int s2 = ssorted[base + j0 + 4 + h];
            int s3 = ssorted[base + j0 + 6 + h];
            uint2 v0 = hp[(size_t)s0 * 32];
            uint2 v1 = hp[(size_t)s1 * 32];
            uint2 v2 = hp[(size_t)s2 * 32];
            uint2 v3 = hp[(size_t)s3 * 32];
            a0 += (lo_bf16(v0.x) + lo_bf16(v1.x)) + (lo_bf16(v2.x) + lo_bf16(v3.x));
            a1 += (hi_bf16(v0.x) + hi_bf16(v1.x)) + (hi_bf16(v2.x) + hi_bf16(v3.x));
            a2 += (lo_bf16(v0.y) + lo_bf16(v1.y)) + (lo_bf16(v2.y) + lo_bf16(v3.y));
            a3 += (hi_bf16(v0.y) + hi_bf16(v1.y)) + (hi_bf16(v2.y) + hi_bf16(v3.y));
        }
        int rem = deg - bulk;
        if (rem > 0) {
            int dm1 = deg - 1;
#pragma unroll
            for (int k = 0; k < 4; k++) {
                int e = j0 + 2 * k + h;
                int s = ssorted[base + min(e, dm1)];
                uint2 v = hp[(size_t)s * 32];
                unsigned mx = (e < deg) ? v.x : 0u;
                unsigned my = (e < deg) ? v.y : 0u;
                a0 += lo_bf16(mx);
                a1 += hi_bf16(mx);
                a2 += lo_bf16(my);
                a3 += hi_bf16(my);
            }
        }
        a0 += __shfl_xor(a0, 32);
        a1 += __shfl_xor(a1, 32);
        a2 += __shfl_xor(a2, 32);
        a3 += __shfl_xor(a3, 32);
        float inv = 1.f / fmaxf((float)deg, 1.f);
        if (h == 0) {
            float4 st = {a0 * inv, a1 * inv, a2 * inv, a3 * inv};
            *reinterpret_cast<float4*>(&aggS[wv][4 * c]) = st;
        }
    }
    __syncthreads();
    if (i < ntar) {
        float e = b2[lane];
#pragma unroll 4
        for (int k = 0; k < DIM; k++) e += aggS[wv][k] * W2s[k * DEMB + lane];
        emb[(size_t)i * DEMB + lane] = e;
    }
}

// ------- AB precompute: rows 0..T-1 = tf_emb@Wm1_top + bm1 ; rows T.. = g_emb@Wm1_bot -------

__global__ __launch_bounds__(128) void ab_kernel(const float* __restrict__ emb,
                                                 const float* __restrict__ Wm1,
                                                 const float* __restrict__ bm1,
                                                 float* __restrict__ AB, int T, int ntar) {
    int i = blockIdx.x;
    int j = threadIdx.x;
    if (i >= ntar) return;
    const float* e = emb + (size_t)i * DEMB;
    int base = (i < T) ? 0 : DEMB;
    float acc = (i < T) ? bm1[j] : 0.f;
#pragma unroll 4
    for (int k = 0; k < DEMB; k++) acc += e[k] * Wm1[(size_t)(base + k) * DIM + j];
    AB[(size_t)i * DIM + j] = acc;
}

// ------- final: out[t,g,:] = softmax via logit-diff sigmoid -------

__global__ __launch_bounds__(256) void final_kernel(const float* __restrict__ AB,
                                                    const float* __restrict__ Wm2,
                                                    const float* __restrict__ bm2,
                                                    float* __restrict__ out, int T, int G) {
    __shared__ float tfAs[8 * DIM];  // 4 KB
    __shared__ float wd[DIM];        // Wm2[:,0]-Wm2[:,1]
    int tid = threadIdx.x;
    int t0 = blockIdx.y * 8;
    int g0 = blockIdx.x * 256;
    {
        int idx = tid * 4;
        int t = t0 + (idx >> 7);
        float4 v = {0, 0, 0, 0};
        if (t < T) v = *reinterpret_cast<const float4*>(&AB[(size_t)t0 * DIM + idx]);
        *reinterpret_cast<float4*>(&tfAs[idx]) = v;
    }
    if (tid < DIM) wd[tid] = Wm2[tid * 2] - Wm2[tid * 2 + 1];
    __syncthreads();
    int g = g0 + tid;
    int gc = min(g, G - 1);
    const float4* gp = reinterpret_cast<const float4*>(AB + (size_t)(T + gc) * DIM);
    float acc[8];
#pragma unroll
    for (int t = 0; t < 8; t++) acc[t] = 0.f;
    for (int kc = 0; kc < 16; kc++) {
        float4 ga = gp[kc * 2];
        float4 gb = gp[kc * 2 + 1];
        float4 wa = *reinterpret_cast<const float4*>(&wd[kc * 8]);
        float4 wb = *reinterpret_cast<const float4*>(&wd[kc * 8 + 4]);
#pragma unroll
        for (int t = 0; t < 8; t++) {
            const float4 ta = *reinterpret_cast<const float4*>(&tfAs[t * DIM + kc * 8]);
            const float4 tb = *reinterpret_cast<const float4*>(&tfAs[t * DIM + kc * 8 + 4]);
            acc[t] += fmaxf(ta.x + ga.x, 0.f) * wa.x;
            acc[t] += fmaxf(ta.y + ga.y, 0.f) * wa.y;
            acc[t] += fmaxf(ta.z + ga.z, 0.f) * wa.z;
            acc[t] += fmaxf(ta.w + ga.w, 0.f) * wa.w;
            acc[t] += fmaxf(tb.x + gb.x, 0.f) * wb.x;
            acc[t] += fmaxf(tb.y + gb.y, 0.f) * wb.y;
            acc[t] += fmaxf(tb.z + gb.z, 0.f) * wb.z;
            acc[t] += fmaxf(tb.w + gb.w, 0.f) * wb.w;
        }
    }
    if (g < G) {
        float bd = bm2[0] - bm2[1];
#pragma unroll
        for (int t = 0; t < 8; t++) {
            if (t0 + t < T) {
                float d = acc[t] + bd;                // l0 - l1
                float p0 = 1.f / (1.f + __expf(-d));  // softmax_0
                float2 r = {p0, 1.f - p0};
                *reinterpret_cast<float2*>(&out[((size_t)(t0 + t) * G + g) * 2]) = r;
            }
        }
    }
}

// ---------------- launcher ----------------

extern "C" void kernel_launch(void* const* d_in, const int* in_sizes, int n_in,
                              void* d_out, int out_size, void* d_ws, size_t ws_size,
                              hipStream_t stream) {
    const float* x    = (const float*)d_in[0];
    const float* W1   = (const float*)d_in[1];
    const float* b1   = (const float*)d_in[2];
    const float* W2   = (const float*)d_in[3];
    const float* b2   = (const float*)d_in[4];
    const float* Wm1  = (const float*)d_in[5];
    const float* bm1  = (const float*)d_in[6];
    const float* Wm2  = (const float*)d_in[7];
    const float* bm2  = (const float*)d_in[8];
    const int* ei     = (const int*)d_in[9];
    const int* dnum   = (const int*)d_in[10];
    const int* tfidx  = (const int*)d_in[11];
    const int* geidx  = (const int*)d_in[12];
    float* out = (float*)d_out;

    int n_nodes = in_sizes[0] / DIM;
    int n_edges = in_sizes[9] / 2;
    int T = in_sizes[11];
    int G = in_sizes[12];
    int ntar = T + G;
    int nbuck = (n_nodes + 255) >> 8;  // 313
    const int* srcp = ei;
    const int* dstp = ei + n_edges;

    char* w = (char*)d_ws;
    size_t o = 0;
    auto alloc = [&](size_t bytes) {
        void* p = w + o;
        o += (bytes + 255) & ~(size_t)255;
        return p;
    };
    unsigned* xh   = (unsigned*)alloc((size_t)n_nodes * 64 * 4);   // 20.5 MB packed bf16
    unsigned* Hh   = (unsigned*)alloc((size_t)n_nodes * 64 * 4);   // 20.5 MB packed bf16
    unsigned* Ah   = (unsigned*)alloc((size_t)n_nodes * 64 * 4);   // 20.5 MB packed bf16
    int* ssorted   = (int*)alloc((size_t)n_edges * 4);             // 10.24 MB
    int* counts    = (int*)alloc((size_t)n_nodes * 4);
    int* rowstart  = (int*)alloc((size_t)n_nodes * 4);
    unsigned* W1t  = (unsigned*)alloc(128 * 64 * 4);               // 32 KB bf16 W1^T
    int* bcnt      = (int*)alloc(2048);
    int* bstart    = (int*)alloc(2048);
    int* bcursor   = (int*)alloc(2048);
    // overlays: binned on Hh (dead until gemm1); emb/AB on Ah (dead after gemm1)
    unsigned* binned = Hh;
    float* emb = (float*)Ah;
    float* AB  = (float*)Ah + (4u * 1024u * 1024u / 4u);

    (void)hipMemsetAsync(bcnt, 0, (size_t)nbuck * 4, stream);

    convert_kernel<<<2048, 256, 0, stream>>>(x, xh, n_nodes * 32);
    prep_w1t<<<32, 256, 0, stream>>>(W1, W1t);
    bucket_count<<<1024, 256, 0, stream>>>(dstp, bcnt, n_edges, nbuck);
    bucket_scan<<<1, 512, 0, stream>>>(bcnt, bstart, bcursor, nbuck, n_edges);
    bucket_scatter<<<(n_edges + CHUNK - 1) / CHUNK, 256, 0, stream>>>(srcp, dstp, bcursor,
                                                                      binned, n_edges, nbuck);
    bucket_csr<<<nbuck, 256, 0, stream>>>(binned, bstart, counts, rowstart, ssorted, n_nodes);

    agg_kernel<<<(n_nodes + 3) / 4, 256, 0, stream>>>(xh, rowstart, counts, ssorted, Ah, n_nodes);
    gemm1_mfma<<<(n_nodes + 63) / 64, 256, 0, stream>>>(Ah, W1t, b1, Hh, n_nodes);
    target_kernel<<<(ntar + 3) / 4, 256, 0, stream>>>(Hh, W2, b2, rowstart, counts, ssorted,
                                                      dnum, tfidx, geidx, emb, T, ntar);
    ab_kernel<<<ntar, 128, 0, stream>>>(emb, Wm1, bm1, AB, T, ntar);
    final_kernel<<<dim3((G + 255) / 256, (T + 7) / 8), 256, 0, stream>>>(AB, Wm2, bm2, out, T, G);
}